// Round 18
// baseline (189.885 us; speedup 1.0000x reference)
//
#include <hip/hip_runtime.h>
#include <hip/hip_bf16.h>

typedef __attribute__((ext_vector_type(4))) int i32x4;

#define GLOBAL_CAST(p) (const __attribute__((address_space(1))) void*)(p)
#define LDS_CAST(p)    (__attribute__((address_space(3))) void*)(p)

// ---------------------------------------------------------------------------
// Kernel 1: per-row scale = max(mean(|w|), eps); q = ternary(w) as i8.
// Single-read fast path at K==4096 (4 float4/thread held in registers).
// ---------------------------------------------------------------------------
__global__ __launch_bounds__(256) void scale_quant_kernel(
    const float* __restrict__ w, float* __restrict__ scale,
    signed char* __restrict__ q, int K)
{
    const int row = blockIdx.x;
    const int tid = threadIdx.x;
    const float* wrow = w + (size_t)row * K;
    const int nvec = K >> 2;
    const float4* wv = (const float4*)wrow;

    __shared__ float red[4];
    const int lane = tid & 63, wid = tid >> 6;

    if (nvec == 1024) {
        float4 v[4];
        float s = 0.f;
        #pragma unroll
        for (int j = 0; j < 4; ++j) {
            v[j] = wv[tid + j * 256];
            s += fabsf(v[j].x) + fabsf(v[j].y) + fabsf(v[j].z) + fabsf(v[j].w);
        }
        #pragma unroll
        for (int off = 32; off > 0; off >>= 1) s += __shfl_down(s, off);
        if (lane == 0) red[wid] = s;
        __syncthreads();
        const float total = red[0] + red[1] + red[2] + red[3];
        const float sc = fmaxf(total / (float)K, 1e-6f);
        const float thr = sc * 0.75f;
        if (tid == 0) scale[row] = sc;
        if (q != nullptr) {
            char4* qv = (char4*)(q + (size_t)row * K);
            #pragma unroll
            for (int j = 0; j < 4; ++j) {
                char4 o;
                o.x = (v[j].x >= thr) ? 1 : ((v[j].x <= -thr) ? -1 : 0);
                o.y = (v[j].y >= thr) ? 1 : ((v[j].y <= -thr) ? -1 : 0);
                o.z = (v[j].z >= thr) ? 1 : ((v[j].z <= -thr) ? -1 : 0);
                o.w = (v[j].w >= thr) ? 1 : ((v[j].w <= -thr) ? -1 : 0);
                qv[tid + j * 256] = o;
            }
        }
        return;
    }

    float s = 0.f;
    for (int i = tid; i < nvec; i += blockDim.x) {
        float4 v = wv[i];
        s += fabsf(v.x) + fabsf(v.y) + fabsf(v.z) + fabsf(v.w);
    }
    #pragma unroll
    for (int off = 32; off > 0; off >>= 1) s += __shfl_down(s, off);
    if (lane == 0) red[wid] = s;
    __syncthreads();
    const float total = red[0] + red[1] + red[2] + red[3];
    const float sc = fmaxf(total / (float)K, 1e-6f);
    const float thr = sc * 0.75f;
    if (tid == 0) scale[row] = sc;
    if (q != nullptr) {
        char4* qv = (char4*)(q + (size_t)row * K);
        for (int i = tid; i < nvec; i += blockDim.x) {
            float4 v = wv[i];
            char4 o;
            o.x = (v.x >= thr) ? 1 : ((v.x <= -thr) ? -1 : 0);
            o.y = (v.y >= thr) ? 1 : ((v.y <= -thr) ? -1 : 0);
            o.z = (v.z >= thr) ? 1 : ((v.z <= -thr) ? -1 : 0);
            o.w = (v.w >= thr) ? 1 : ((v.w <= -thr) ? -1 : 0);
            qv[i] = o;
        }
    }
}

// ---------------------------------------------------------------------------
// Kernel 2: per-row symmetric i8 quantization of x; single-read at K==4096.
// ---------------------------------------------------------------------------
__global__ __launch_bounds__(256) void x_quant_kernel(
    const float* __restrict__ x, float* __restrict__ sx,
    signed char* __restrict__ xq, int K)
{
    const int row = blockIdx.x;
    const int tid = threadIdx.x;
    const float4* xv = (const float4*)(x + (size_t)row * K);
    const int nvec = K >> 2;

    __shared__ float red[4];
    const int lane = tid & 63, wid = tid >> 6;

    if (nvec == 1024) {
        float4 v[4];
        float am = 0.f;
        #pragma unroll
        for (int j = 0; j < 4; ++j) {
            v[j] = xv[tid + j * 256];
            am = fmaxf(am, fmaxf(fmaxf(fabsf(v[j].x), fabsf(v[j].y)),
                                 fmaxf(fabsf(v[j].z), fabsf(v[j].w))));
        }
        #pragma unroll
        for (int off = 32; off > 0; off >>= 1) am = fmaxf(am, __shfl_down(am, off));
        if (lane == 0) red[wid] = am;
        __syncthreads();
        const float amax = fmaxf(fmaxf(red[0], red[1]), fmaxf(red[2], red[3]));
        const float inv = (amax > 0.f) ? (127.f / amax) : 0.f;
        if (tid == 0) sx[row] = amax * (1.f / 127.f);
        char4* qv = (char4*)(xq + (size_t)row * K);
        #pragma unroll
        for (int j = 0; j < 4; ++j) {
            char4 o;
            o.x = (signed char)__float2int_rn(v[j].x * inv);
            o.y = (signed char)__float2int_rn(v[j].y * inv);
            o.z = (signed char)__float2int_rn(v[j].z * inv);
            o.w = (signed char)__float2int_rn(v[j].w * inv);
            qv[tid + j * 256] = o;
        }
        return;
    }

    float am = 0.f;
    for (int i = tid; i < nvec; i += blockDim.x) {
        float4 v = xv[i];
        am = fmaxf(am, fmaxf(fmaxf(fabsf(v.x), fabsf(v.y)), fmaxf(fabsf(v.z), fabsf(v.w))));
    }
    #pragma unroll
    for (int off = 32; off > 0; off >>= 1) am = fmaxf(am, __shfl_down(am, off));
    if (lane == 0) red[wid] = am;
    __syncthreads();
    const float amax = fmaxf(fmaxf(red[0], red[1]), fmaxf(red[2], red[3]));
    const float inv = (amax > 0.f) ? (127.f / amax) : 0.f;
    if (tid == 0) sx[row] = amax * (1.f / 127.f);
    char4* qv = (char4*)(xq + (size_t)row * K);
    for (int i = tid; i < nvec; i += blockDim.x) {
        float4 v = xv[i];
        char4 o;
        o.x = (signed char)__float2int_rn(v.x * inv);
        o.y = (signed char)__float2int_rn(v.y * inv);
        o.z = (signed char)__float2int_rn(v.z * inv);
        o.w = (signed char)__float2int_rn(v.w * inv);
        qv[i] = o;
    }
}

// ---------------------------------------------------------------------------
// Kernel 3: 256x256 i8 GEMM, ANTI-PHASE + RING-5 region rotation (160 KiB).
//   out[m][n] = sx[m]*scale[n] * (sum_k xq[m][k]*q[n][k]) + bias[n]
// 512 thr = 8 waves (2M x 4N); per-wave 128x64 out = acc[8][4] i32x4.
// LDS 160 KiB = 5 regions x 32 KiB. Region = one k-slice (64 i8) of the
// K-tile: {A 256x64 (16K) | B 256x64 (16K)}, row stride 64 B, r10's proven
// 0-conflict swizzle: slot s of row r holds chunk s ^ ((r>>1)&3); dest
// LINEAR (rule 21), source column pre-swizzled.
// Phase phi = one slice (12 ds_read + 32 MFMA). Anti-phase (r17 win kept):
// g0 (wm=0) reads regions (2t, 2t+1); g1 (wm=1) swapped -> each SIMD holds
// one wave of each order; LDS and matrix pipes overlap.
// Ring-5 staging: stage region phi+3 during phase phi (4 gload_lds, issue
// order pinned by sched_barrier); pair-end wait = vmcnt(4) (only newest
// region outstanding) -- NEVER drains in steady state (removes r17's
// tile-end vmcnt(0) stall). Tail: vmcnt(0) at t >= NT-2. Race audit:
// stage at phi overwrites region phi-2, last read before the previous
// pair-end barrier (both groups); g1's read-ahead region phi+1 guaranteed
// by previous pair's vmcnt(4)+barrier. Prologue drains vmcnt(0)
// (order-independent; r14 lesson). One s_barrier per K-tile.
// i32 accumulation exact; error = X-quant only.
// ---------------------------------------------------------------------------
#define BM 256
#define BN 256
#define BK 128
#define REG 32768u
#define LDS5 163840u

__global__ __launch_bounds__(512, 1) void gemm256_i8_kernel(
    const signed char* __restrict__ Xq,   // [M][K] i8
    const signed char* __restrict__ Qq,   // [N][K] i8
    const float* __restrict__ sx,         // [M]
    const float* __restrict__ scale,      // [N]
    const float* __restrict__ bias,       // [N]
    float* __restrict__ out, int M, int N, int K)
{
    __shared__ __align__(16) char lds[LDS5];

    const int tid  = threadIdx.x;
    const int lane = tid & 63;
    const int wid  = tid >> 6;       // 0..7
    const int wm   = wid >> 2;       // 0..1  (M half of tile) = anti-phase grp
    const int wn   = wid & 3;        // 0..3  (N quarter)
    const int kh   = lane >> 4;      // 0..3
    const int lr   = lane & 15;

    // XCD-bijective swizzle (grid % 8 == 0 guaranteed by host gate)
    int bid = blockIdx.x;
    const int nwg = gridDim.x;
    if ((nwg & 7) == 0) { const int cpx = nwg >> 3; bid = (bid & 7) * cpx + (bid >> 3); }
    const int nbn = N / BN;
    const int tm = bid / nbn, tn = bid % nbn;
    const int arow0 = tm * BM;
    const int brow0 = tn * BN;
    const int NT = K / BK;

    // ---- within-region LDS read byte-offsets ----
    unsigned aoff[8], boff[4];
    #pragma unroll
    for (int mf = 0; mf < 8; ++mf) {
        const int row = wm * 128 + mf * 16 + lr;
        aoff[mf] = (unsigned)(row * 64 + ((kh ^ ((row >> 1) & 3)) << 4));
    }
    #pragma unroll
    for (int nf = 0; nf < 4; ++nf) {
        const int row = wn * 64 + nf * 16 + lr;
        boff[nf] = 16384u + (unsigned)(row * 64 + ((kh ^ ((row >> 1) & 3)) << 4));
    }

    // ---- staging: per region 1024 A-chunks + 1024 B-chunks; 2+2 per thread --
    // chunk ci: r = ci>>2, s = ci&3; dest LINEAR ci*16; src col = (s^((r>>1)&3))*16
    const int rA0 = tid >> 2, sA0 = tid & 3;
    const int colA0 = (sA0 ^ ((rA0 >> 1) & 3)) << 4;
    const int rA1 = rA0 + 128;                      // ci = tid + 512
    const int colA1 = (sA0 ^ ((rA1 >> 1) & 3)) << 4;
    const unsigned dA0 = (unsigned)(tid * 16);
    const unsigned dA1 = (unsigned)((tid + 512) * 16);
    const unsigned dB0 = 16384u + dA0;
    const unsigned dB1 = 16384u + dA1;

    // running stage source pointers (advance +64 i8 per region staged)
    const signed char* aS0 = Xq + (size_t)(arow0 + rA0) * K + colA0;
    const signed char* aS1 = Xq + (size_t)(arow0 + rA1) * K + colA1;
    const signed char* bS0 = Qq + (size_t)(brow0 + rA0) * K + colA0;
    const signed char* bS1 = Qq + (size_t)(brow0 + rA1) * K + colA1;

    // ---- prologue: stage regions 0,1,2 (slots 0,1,2); drain; barrier ----
    #pragma unroll
    for (int rho = 0; rho < 3; ++rho) {
        const unsigned sb = (unsigned)rho * REG;
        __builtin_amdgcn_global_load_lds(GLOBAL_CAST(aS0), LDS_CAST(lds + (sb | dA0)), 16, 0, 0);
        __builtin_amdgcn_global_load_lds(GLOBAL_CAST(aS1), LDS_CAST(lds + (sb | dA1)), 16, 0, 0);
        __builtin_amdgcn_global_load_lds(GLOBAL_CAST(bS0), LDS_CAST(lds + (sb | dB0)), 16, 0, 0);
        __builtin_amdgcn_global_load_lds(GLOBAL_CAST(bS1), LDS_CAST(lds + (sb | dB1)), 16, 0, 0);
        aS0 += 64; aS1 += 64; bS0 += 64; bS1 += 64;
    }
    asm volatile("s_waitcnt vmcnt(0)" ::: "memory");
    __builtin_amdgcn_sched_barrier(0);
    __builtin_amdgcn_s_barrier();

    i32x4 acc[8][4] = {};
    i32x4 a[8], b[4];

    #define PHASE(RB)                                                          \
        _Pragma("unroll")                                                      \
        for (int nf = 0; nf < 4; ++nf)                                         \
            b[nf] = *(const i32x4*)(lds + ((RB) + boff[nf]));                  \
        _Pragma("unroll")                                                      \
        for (int mf = 0; mf < 8; ++mf)                                         \
            a[mf] = *(const i32x4*)(lds + ((RB) + aoff[mf]));                  \
        __builtin_amdgcn_s_setprio(1);                                         \
        _Pragma("unroll")                                                      \
        for (int mf = 0; mf < 8; ++mf)                                         \
            _Pragma("unroll")                                                  \
            for (int nf = 0; nf < 4; ++nf)                                     \
                acc[mf][nf] = __builtin_amdgcn_mfma_i32_16x16x64_i8(           \
                    a[mf], b[nf], acc[mf][nf], 0, 0, 0);                       \
        __builtin_amdgcn_s_setprio(0);

    #define STAGE(SB) {                                                        \
        __builtin_amdgcn_global_load_lds(GLOBAL_CAST(aS0), LDS_CAST(lds + ((SB) | dA0)), 16, 0, 0); \
        __builtin_amdgcn_global_load_lds(GLOBAL_CAST(aS1), LDS_CAST(lds + ((SB) | dA1)), 16, 0, 0); \
        __builtin_amdgcn_global_load_lds(GLOBAL_CAST(bS0), LDS_CAST(lds + ((SB) | dB0)), 16, 0, 0); \
        __builtin_amdgcn_global_load_lds(GLOBAL_CAST(bS1), LDS_CAST(lds + ((SB) | dB1)), 16, 0, 0); \
        aS0 += 64; aS1 += 64; bS0 += 64; bS1 += 64;                            \
        __builtin_amdgcn_sched_barrier(0); }

    unsigned base0 = 0u;             // region 2t   slot base
    unsigned base1 = REG;            // region 2t+1 slot base
    unsigned sbase = 3u * REG;       // stage target slot (region 3 first)
    const int NPH = 2 * NT;

    for (int t = 0; t < NT; ++t) {
        const unsigned rbF = wm ? base1 : base0;   // group's first slice
        const unsigned rbS = wm ? base0 : base1;   // group's second slice

        // ---- phase even (2t): stage region 2t+3 ----
        if (2 * t + 3 < NPH) {
            STAGE(sbase)
            sbase += REG; if (sbase >= LDS5) sbase = 0u;
        }
        PHASE(rbF)

        // ---- phase odd (2t+1): stage region 2t+4 ----
        if (2 * t + 4 < NPH) {
            STAGE(sbase)
            sbase += REG; if (sbase >= LDS5) sbase = 0u;
        }
        PHASE(rbS)

        // ---- pair end: counted wait (never drain until tail) + barrier ----
        base0 += 2u * REG; if (base0 >= LDS5) base0 -= LDS5;
        base1 = base0 + REG; if (base1 >= LDS5) base1 -= LDS5;
        if (t < NT - 2) { asm volatile("s_waitcnt vmcnt(4)" ::: "memory"); }
        else            { asm volatile("s_waitcnt vmcnt(0)" ::: "memory"); }
        __builtin_amdgcn_sched_barrier(0);
        __builtin_amdgcn_s_barrier();
    }
    #undef PHASE
    #undef STAGE

    // epilogue: out = sx[m]*scale[n]*acc + bias[n]
    // D layout: col = lane&15, row = (lane>>4)*4 + r
    float sxv[32];
    #pragma unroll
    for (int mf = 0; mf < 8; ++mf)
        #pragma unroll
        for (int r = 0; r < 4; ++r)
            sxv[mf * 4 + r] = sx[arow0 + wm * 128 + mf * 16 + kh * 4 + r];

    #pragma unroll
    for (int nf = 0; nf < 4; ++nf) {
        const int gn = brow0 + wn * 64 + nf * 16 + lr;
        const float sc = scale[gn];
        const float bs = bias[gn];
        #pragma unroll
        for (int mf = 0; mf < 8; ++mf) {
            const size_t gm = (size_t)arow0 + wm * 128 + mf * 16 + kh * 4;
            #pragma unroll
            for (int r = 0; r < 4; ++r)
                out[(gm + r) * (size_t)N + gn] =
                    (float)acc[mf][nf][r] * (sxv[mf * 4 + r] * sc) + bs;
        }
    }
}

// ---------------------------------------------------------------------------
// Fallback: fp32 smem-tiled GEMM, quantize on the fly.
// ---------------------------------------------------------------------------
__global__ __launch_bounds__(256) void fb_gemm_kernel(
    const float* __restrict__ X, const float* __restrict__ W,
    const float* __restrict__ scale, const float* __restrict__ bias,
    float* __restrict__ out, int M, int N, int K)
{
    __shared__ float xs[16][16];
    __shared__ float qs[16][17];
    const int tx = threadIdx.x & 15, ty = threadIdx.x >> 4;
    const int m = blockIdx.y * 16 + ty;
    const int n = blockIdx.x * 16 + tx;
    const int nrow = blockIdx.x * 16 + ty;
    const int mL = min(m, M - 1);
    const int nrowL = min(nrow, N - 1);
    const float thr = scale[nrowL] * 0.75f;
    float acc = 0.f;
    for (int k0 = 0; k0 < K; k0 += 16) {
        xs[ty][tx] = X[(size_t)mL * K + k0 + tx];
        const float w = W[(size_t)nrowL * K + k0 + tx];
        qs[ty][tx] = (w >= thr) ? 1.f : ((w <= -thr) ? -1.f : 0.f);
        __syncthreads();
        #pragma unroll
        for (int kk = 0; kk < 16; ++kk) acc += xs[ty][kk] * qs[tx][kk];
        __syncthreads();
    }
    if (m < M && n < N) out[(size_t)m * N + n] = scale[n] * acc + bias[n];
}

// ---------------------------------------------------------------------------
extern "C" void kernel_launch(void* const* d_in, const int* in_sizes, int n_in,
                              void* d_out, int out_size, void* d_ws, size_t ws_size,
                              hipStream_t stream)
{
    const float* x    = (const float*)d_in[0];
    const float* w    = (const float*)d_in[1];
    const float* bias = (const float*)d_in[2];
    float* out = (float*)d_out;

    const int N = in_sizes[2];             // OUT
    const int K = in_sizes[1] / N;         // IN
    const int M = in_sizes[0] / K;         // B

    const size_t scOff = 0;
    const size_t sxOff = (scOff + (size_t)N * 4 + 255) & ~(size_t)255;
    const size_t qOff  = (sxOff + (size_t)M * 4 + 255) & ~(size_t)255;
    const size_t xqOff = (qOff + (size_t)N * K + 255) & ~(size_t)255;
    const size_t need  = xqOff + (size_t)M * K;

    float* scale = (float*)((char*)d_ws + scOff);

    const bool fast = (ws_size >= need) &&
                      (M % BM == 0) && (N % BN == 0) && (K % BK == 0) &&
                      ((K & 3) == 0) && (K / BK >= 4) &&
                      (((M / BM) * (N / BN)) % 8 == 0);

    if (fast) {
        float* sx        = (float*)((char*)d_ws + sxOff);
        signed char* q   = (signed char*)((char*)d_ws + qOff);
        signed char* xq  = (signed char*)((char*)d_ws + xqOff);

        scale_quant_kernel<<<N, 256, 0, stream>>>(w, scale, q, K);
        x_quant_kernel<<<M, 256, 0, stream>>>(x, sx, xq, K);

        const int grid = (M / BM) * (N / BN);
        gemm256_i8_kernel<<<grid, 512, 0, stream>>>(xq, q, sx, scale, bias, out, M, N, K);
    } else {
        scale_quant_kernel<<<N, 256, 0, stream>>>(w, scale, nullptr, K);
        dim3 g((N + 15) / 16, (M + 15) / 16);
        fb_gemm_kernel<<<g, 256, 0, stream>>>(x, w, scale, bias, out, M, N, K);
    }
}

// Round 19
// 181.189 us; speedup vs baseline: 1.0480x; 1.0480x over previous
//
#include <hip/hip_runtime.h>
#include <hip/hip_bf16.h>

typedef __attribute__((ext_vector_type(4))) int i32x4;

#define GLOBAL_CAST(p) (const __attribute__((address_space(1))) void*)(p)
#define LDS_CAST(p)    (__attribute__((address_space(3))) void*)(p)

// ---------------------------------------------------------------------------
// Kernel 1: per-row scale = max(mean(|w|), eps); q = ternary(w) as i8.
// Single-read fast path at K==4096 (4 float4/thread held in registers).
// ---------------------------------------------------------------------------
__global__ __launch_bounds__(256) void scale_quant_kernel(
    const float* __restrict__ w, float* __restrict__ scale,
    signed char* __restrict__ q, int K)
{
    const int row = blockIdx.x;
    const int tid = threadIdx.x;
    const float* wrow = w + (size_t)row * K;
    const int nvec = K >> 2;
    const float4* wv = (const float4*)wrow;

    __shared__ float red[4];
    const int lane = tid & 63, wid = tid >> 6;

    if (nvec == 1024) {
        float4 v[4];
        float s = 0.f;
        #pragma unroll
        for (int j = 0; j < 4; ++j) {
            v[j] = wv[tid + j * 256];
            s += fabsf(v[j].x) + fabsf(v[j].y) + fabsf(v[j].z) + fabsf(v[j].w);
        }
        #pragma unroll
        for (int off = 32; off > 0; off >>= 1) s += __shfl_down(s, off);
        if (lane == 0) red[wid] = s;
        __syncthreads();
        const float total = red[0] + red[1] + red[2] + red[3];
        const float sc = fmaxf(total / (float)K, 1e-6f);
        const float thr = sc * 0.75f;
        if (tid == 0) scale[row] = sc;
        if (q != nullptr) {
            char4* qv = (char4*)(q + (size_t)row * K);
            #pragma unroll
            for (int j = 0; j < 4; ++j) {
                char4 o;
                o.x = (v[j].x >= thr) ? 1 : ((v[j].x <= -thr) ? -1 : 0);
                o.y = (v[j].y >= thr) ? 1 : ((v[j].y <= -thr) ? -1 : 0);
                o.z = (v[j].z >= thr) ? 1 : ((v[j].z <= -thr) ? -1 : 0);
                o.w = (v[j].w >= thr) ? 1 : ((v[j].w <= -thr) ? -1 : 0);
                qv[tid + j * 256] = o;
            }
        }
        return;
    }

    float s = 0.f;
    for (int i = tid; i < nvec; i += blockDim.x) {
        float4 v = wv[i];
        s += fabsf(v.x) + fabsf(v.y) + fabsf(v.z) + fabsf(v.w);
    }
    #pragma unroll
    for (int off = 32; off > 0; off >>= 1) s += __shfl_down(s, off);
    if (lane == 0) red[wid] = s;
    __syncthreads();
    const float total = red[0] + red[1] + red[2] + red[3];
    const float sc = fmaxf(total / (float)K, 1e-6f);
    const float thr = sc * 0.75f;
    if (tid == 0) scale[row] = sc;
    if (q != nullptr) {
        char4* qv = (char4*)(q + (size_t)row * K);
        for (int i = tid; i < nvec; i += blockDim.x) {
            float4 v = wv[i];
            char4 o;
            o.x = (v.x >= thr) ? 1 : ((v.x <= -thr) ? -1 : 0);
            o.y = (v.y >= thr) ? 1 : ((v.y <= -thr) ? -1 : 0);
            o.z = (v.z >= thr) ? 1 : ((v.z <= -thr) ? -1 : 0);
            o.w = (v.w >= thr) ? 1 : ((v.w <= -thr) ? -1 : 0);
            qv[i] = o;
        }
    }
}

// ---------------------------------------------------------------------------
// Kernel 2: per-row symmetric i8 quantization of x; single-read at K==4096.
// ---------------------------------------------------------------------------
__global__ __launch_bounds__(256) void x_quant_kernel(
    const float* __restrict__ x, float* __restrict__ sx,
    signed char* __restrict__ xq, int K)
{
    const int row = blockIdx.x;
    const int tid = threadIdx.x;
    const float4* xv = (const float4*)(x + (size_t)row * K);
    const int nvec = K >> 2;

    __shared__ float red[4];
    const int lane = tid & 63, wid = tid >> 6;

    if (nvec == 1024) {
        float4 v[4];
        float am = 0.f;
        #pragma unroll
        for (int j = 0; j < 4; ++j) {
            v[j] = xv[tid + j * 256];
            am = fmaxf(am, fmaxf(fmaxf(fabsf(v[j].x), fabsf(v[j].y)),
                                 fmaxf(fabsf(v[j].z), fabsf(v[j].w))));
        }
        #pragma unroll
        for (int off = 32; off > 0; off >>= 1) am = fmaxf(am, __shfl_down(am, off));
        if (lane == 0) red[wid] = am;
        __syncthreads();
        const float amax = fmaxf(fmaxf(red[0], red[1]), fmaxf(red[2], red[3]));
        const float inv = (amax > 0.f) ? (127.f / amax) : 0.f;
        if (tid == 0) sx[row] = amax * (1.f / 127.f);
        char4* qv = (char4*)(xq + (size_t)row * K);
        #pragma unroll
        for (int j = 0; j < 4; ++j) {
            char4 o;
            o.x = (signed char)__float2int_rn(v[j].x * inv);
            o.y = (signed char)__float2int_rn(v[j].y * inv);
            o.z = (signed char)__float2int_rn(v[j].z * inv);
            o.w = (signed char)__float2int_rn(v[j].w * inv);
            qv[tid + j * 256] = o;
        }
        return;
    }

    float am = 0.f;
    for (int i = tid; i < nvec; i += blockDim.x) {
        float4 v = xv[i];
        am = fmaxf(am, fmaxf(fmaxf(fabsf(v.x), fabsf(v.y)), fmaxf(fabsf(v.z), fabsf(v.w))));
    }
    #pragma unroll
    for (int off = 32; off > 0; off >>= 1) am = fmaxf(am, __shfl_down(am, off));
    if (lane == 0) red[wid] = am;
    __syncthreads();
    const float amax = fmaxf(fmaxf(red[0], red[1]), fmaxf(red[2], red[3]));
    const float inv = (amax > 0.f) ? (127.f / amax) : 0.f;
    if (tid == 0) sx[row] = amax * (1.f / 127.f);
    char4* qv = (char4*)(xq + (size_t)row * K);
    for (int i = tid; i < nvec; i += blockDim.x) {
        float4 v = xv[i];
        char4 o;
        o.x = (signed char)__float2int_rn(v.x * inv);
        o.y = (signed char)__float2int_rn(v.y * inv);
        o.z = (signed char)__float2int_rn(v.z * inv);
        o.w = (signed char)__float2int_rn(v.w * inv);
        qv[i] = o;
    }
}

// ---------------------------------------------------------------------------
// Kernel 3: 256x256 i8 GEMM (mfma_i32_16x16x64_i8), WAVE ANTI-PHASE (r17).
//   out[m][n] = sx[m]*scale[n] * (sum_k xq[m][k]*q[n][k]) + bias[n]
// 512 thr = 8 waves (2M x 4N); per-wave 128x64 out = acc[8][4] i32x4.
// LDS 128 KiB: 2 dbuf x {A 256x128i8 | B 256x128i8}; chunk swizzle (slot s
// of row r holds global chunk s^(r&7); dest LINEAR, source pre-swizzled;
// 0 conflicts measured).
// ANTI-PHASE: K-tile = 2 independent k-slices (addr(ks) = addr(0)^(ks<<6)).
// Waves 0-3 process ks0->ks1; waves 4-7 ks1->ks0 (each SIMD holds one wave
// of each order) -> at any instant ~half the waves MFMA while half ds_read;
// measured: 4920 -> 4561 cyc/K-tile, MfmaUtil 39 -> 42%, GEMM 150 -> 139us.
// Tile-end vmcnt(0)+barrier (order-independent). Prologue drains vmcnt(0).
// i32 accumulation exact; error = X-quant only.
// ---------------------------------------------------------------------------
#define BM 256
#define BN 256
#define BK 128

__global__ __launch_bounds__(512, 2) void gemm256_i8_kernel(
    const signed char* __restrict__ Xq,   // [M][K] i8
    const signed char* __restrict__ Qq,   // [N][K] i8
    const float* __restrict__ sx,         // [M]
    const float* __restrict__ scale,      // [N]
    const float* __restrict__ bias,       // [N]
    float* __restrict__ out, int M, int N, int K)
{
    __shared__ __align__(16) char lds[131072];

    const int tid  = threadIdx.x;
    const int lane = tid & 63;
    const int wid  = tid >> 6;       // 0..7
    const int wm   = wid >> 2;       // 0..1  (M half of tile)
    const int wn   = wid & 3;        // 0..3  (N quarter)
    const int kh   = lane >> 4;      // 0..3
    const int lr   = lane & 15;
    const int grp  = wm;             // anti-phase group: one per SIMD pair

    // XCD-bijective swizzle (grid % 8 == 0 guaranteed by host gate)
    int bid = blockIdx.x;
    const int nwg = gridDim.x;
    if ((nwg & 7) == 0) { const int cpx = nwg >> 3; bid = (bid & 7) * cpx + (bid >> 3); }
    const int nbn = N / BN;
    const int tm = bid / nbn, tn = bid % nbn;
    const int arow0 = tm * BM;
    const int brow0 = tn * BN;
    const int NT = K / BK;

    // ---- LDS read byte-offsets for ks=0 (buffer toggle: |tb ; ks: ^(ks<<6)) --
    unsigned aoff[8], boff[4];
    #pragma unroll
    for (int mf = 0; mf < 8; ++mf) {
        const int row = wm * 128 + mf * 16 + lr;
        aoff[mf] = (unsigned)(row * 128 + ((kh ^ (row & 7)) << 4));
    }
    #pragma unroll
    for (int nf = 0; nf < 4; ++nf) {
        const int row = wn * 64 + nf * 16 + lr;
        boff[nf] = (unsigned)(32768 + row * 128 + ((kh ^ (row & 7)) << 4));
    }

    // ---- stage streams: running global pointers + fixed LDS dest offs ----
    const int r0 = tid >> 3;
    const int c0 = (((tid & 7) ^ (r0 & 7)) << 4);
    const int ci1 = 512 + tid;
    const int r1 = ci1 >> 3;
    const int c1 = (((ci1 & 7) ^ (r1 & 7)) << 4);

    const signed char* asrc[2][2];
    const signed char* bsrc[2][2];
    unsigned adst[2][2], bdst[2][2];
    #pragma unroll
    for (int hh = 0; hh < 2; ++hh) {
        asrc[hh][0] = Xq + (size_t)(arow0 + hh * 128 + r0) * K + BK + c0;   // A(t+1)
        asrc[hh][1] = Xq + (size_t)(arow0 + hh * 128 + r1) * K + BK + c1;
        bsrc[hh][0] = Qq + (size_t)(brow0 + hh * 128 + r0) * K + BK + c0;   // B(t+1)
        bsrc[hh][1] = Qq + (size_t)(brow0 + hh * 128 + r1) * K + BK + c1;
        adst[hh][0] = (unsigned)(hh * 16384 + tid * 16);
        adst[hh][1] = (unsigned)(hh * 16384 + ci1 * 16);
        bdst[hh][0] = (unsigned)(32768 + hh * 16384 + tid * 16);
        bdst[hh][1] = (unsigned)(32768 + hh * 16384 + ci1 * 16);
    }

    // ---- prologue: stage tile 0 {A0,A1,B0,B1} into buffer 0 ----
    #pragma unroll
    for (int hh = 0; hh < 2; ++hh) {
        const int rowA = arow0 + hh * 128, rowB = brow0 + hh * 128;
        const signed char* ga0 = Xq + (size_t)(rowA + r0) * K + c0;
        const signed char* ga1 = Xq + (size_t)(rowA + r1) * K + c1;
        const signed char* gb0 = Qq + (size_t)(rowB + r0) * K + c0;
        const signed char* gb1 = Qq + (size_t)(rowB + r1) * K + c1;
        __builtin_amdgcn_global_load_lds(GLOBAL_CAST(ga0), LDS_CAST(lds + adst[hh][0]), 16, 0, 0);
        __builtin_amdgcn_global_load_lds(GLOBAL_CAST(ga1), LDS_CAST(lds + adst[hh][1]), 16, 0, 0);
        __builtin_amdgcn_global_load_lds(GLOBAL_CAST(gb0), LDS_CAST(lds + bdst[hh][0]), 16, 0, 0);
        __builtin_amdgcn_global_load_lds(GLOBAL_CAST(gb1), LDS_CAST(lds + bdst[hh][1]), 16, 0, 0);
    }
    asm volatile("s_waitcnt vmcnt(0)" ::: "memory");
    __builtin_amdgcn_sched_barrier(0);
    __builtin_amdgcn_s_barrier();

    i32x4 acc[8][4] = {};
    i32x4 a[8], b[4];

    #define PHASE(KX)                                                          \
        _Pragma("unroll")                                                      \
        for (int nf = 0; nf < 4; ++nf)                                         \
            b[nf] = *(const i32x4*)(lds + ((tb | boff[nf]) ^ (KX)));           \
        _Pragma("unroll")                                                      \
        for (int mf = 0; mf < 8; ++mf)                                         \
            a[mf] = *(const i32x4*)(lds + ((tb | aoff[mf]) ^ (KX)));           \
        __builtin_amdgcn_s_setprio(1);                                         \
        _Pragma("unroll")                                                      \
        for (int mf = 0; mf < 8; ++mf)                                         \
            _Pragma("unroll")                                                  \
            for (int nf = 0; nf < 4; ++nf)                                     \
                acc[mf][nf] = __builtin_amdgcn_mfma_i32_16x16x64_i8(           \
                    a[mf], b[nf], acc[mf][nf], 0, 0, 0);                       \
        __builtin_amdgcn_s_setprio(0);

    const unsigned kx0 = (unsigned)grp << 6;        // group's first slice
    const unsigned kx1 = kx0 ^ 64u;                 // group's second slice

    for (int t = 0; t < NT; ++t) {
        const unsigned tb = (unsigned)(t & 1) << 16;
        const unsigned ta = tb ^ 0x10000u;
        const bool doS = (t < NT - 1);

        // ---- phase 0: stage A(t+1); compute slice kx0 ----
        if (doS) {
            #pragma unroll
            for (int hh = 0; hh < 2; ++hh) {
                __builtin_amdgcn_global_load_lds(GLOBAL_CAST(asrc[hh][0]), LDS_CAST(lds + (ta | adst[hh][0])), 16, 0, 0);
                __builtin_amdgcn_global_load_lds(GLOBAL_CAST(asrc[hh][1]), LDS_CAST(lds + (ta | adst[hh][1])), 16, 0, 0);
            }
        }
        PHASE(kx0)

        // ---- phase 1: stage B(t+1); compute slice kx1 ----
        if (doS) {
            #pragma unroll
            for (int hh = 0; hh < 2; ++hh) {
                __builtin_amdgcn_global_load_lds(GLOBAL_CAST(bsrc[hh][0]), LDS_CAST(lds + (ta | bdst[hh][0])), 16, 0, 0);
                __builtin_amdgcn_global_load_lds(GLOBAL_CAST(bsrc[hh][1]), LDS_CAST(lds + (ta | bdst[hh][1])), 16, 0, 0);
            }
        }
        PHASE(kx1)

        // advance stage streams (BK i8 = 128 B)
        #pragma unroll
        for (int hh = 0; hh < 2; ++hh) {
            asrc[hh][0] += BK; asrc[hh][1] += BK;
            bsrc[hh][0] += BK; bsrc[hh][1] += BK;
        }
        asm volatile("s_waitcnt vmcnt(0)" ::: "memory");
        __builtin_amdgcn_sched_barrier(0);
        __builtin_amdgcn_s_barrier();
    }
    #undef PHASE

    // epilogue: out = sx[m]*scale[n]*acc + bias[n]
    // D layout: col = lane&15, row = (lane>>4)*4 + r
    float sxv[32];
    #pragma unroll
    for (int mf = 0; mf < 8; ++mf)
        #pragma unroll
        for (int r = 0; r < 4; ++r)
            sxv[mf * 4 + r] = sx[arow0 + wm * 128 + mf * 16 + kh * 4 + r];

    #pragma unroll
    for (int nf = 0; nf < 4; ++nf) {
        const int gn = brow0 + wn * 64 + nf * 16 + lr;
        const float sc = scale[gn];
        const float bs = bias[gn];
        #pragma unroll
        for (int mf = 0; mf < 8; ++mf) {
            const size_t gm = (size_t)arow0 + wm * 128 + mf * 16 + kh * 4;
            #pragma unroll
            for (int r = 0; r < 4; ++r)
                out[(gm + r) * (size_t)N + gn] =
                    (float)acc[mf][nf][r] * (sxv[mf * 4 + r] * sc) + bs;
        }
    }
}

// ---------------------------------------------------------------------------
// Fallback: fp32 smem-tiled GEMM, quantize on the fly.
// ---------------------------------------------------------------------------
__global__ __launch_bounds__(256) void fb_gemm_kernel(
    const float* __restrict__ X, const float* __restrict__ W,
    const float* __restrict__ scale, const float* __restrict__ bias,
    float* __restrict__ out, int M, int N, int K)
{
    __shared__ float xs[16][16];
    __shared__ float qs[16][17];
    const int tx = threadIdx.x & 15, ty = threadIdx.x >> 4;
    const int m = blockIdx.y * 16 + ty;
    const int n = blockIdx.x * 16 + tx;
    const int nrow = blockIdx.x * 16 + ty;
    const int mL = min(m, M - 1);
    const int nrowL = min(nrow, N - 1);
    const float thr = scale[nrowL] * 0.75f;
    float acc = 0.f;
    for (int k0 = 0; k0 < K; k0 += 16) {
        xs[ty][tx] = X[(size_t)mL * K + k0 + tx];
        const float w = W[(size_t)nrowL * K + k0 + tx];
        qs[ty][tx] = (w >= thr) ? 1.f : ((w <= -thr) ? -1.f : 0.f);
        __syncthreads();
        #pragma unroll
        for (int kk = 0; kk < 16; ++kk) acc += xs[ty][kk] * qs[tx][kk];
        __syncthreads();
    }
    if (m < M && n < N) out[(size_t)m * N + n] = scale[n] * acc + bias[n];
}

// ---------------------------------------------------------------------------
extern "C" void kernel_launch(void* const* d_in, const int* in_sizes, int n_in,
                              void* d_out, int out_size, void* d_ws, size_t ws_size,
                              hipStream_t stream)
{
    const float* x    = (const float*)d_in[0];
    const float* w    = (const float*)d_in[1];
    const float* bias = (const float*)d_in[2];
    float* out = (float*)d_out;

    const int N = in_sizes[2];             // OUT
    const int K = in_sizes[1] / N;         // IN
    const int M = in_sizes[0] / K;         // B

    const size_t scOff = 0;
    const size_t sxOff = (scOff + (size_t)N * 4 + 255) & ~(size_t)255;
    const size_t qOff  = (sxOff + (size_t)M * 4 + 255) & ~(size_t)255;
    const size_t xqOff = (qOff + (size_t)N * K + 255) & ~(size_t)255;
    const size_t need  = xqOff + (size_t)M * K;

    float* scale = (float*)((char*)d_ws + scOff);

    const bool fast = (ws_size >= need) &&
                      (M % BM == 0) && (N % BN == 0) && (K % BK == 0) &&
                      ((K & 3) == 0) && (K / BK >= 4) &&
                      (((M / BM) * (N / BN)) % 8 == 0);

    if (fast) {
        float* sx        = (float*)((char*)d_ws + sxOff);
        signed char* q   = (signed char*)((char*)d_ws + qOff);
        signed char* xq  = (signed char*)((char*)d_ws + xqOff);

        scale_quant_kernel<<<N, 256, 0, stream>>>(w, scale, q, K);
        x_quant_kernel<<<M, 256, 0, stream>>>(x, sx, xq, K);

        const int grid = (M / BM) * (N / BN);
        gemm256_i8_kernel<<<grid, 512, 0, stream>>>(xq, q, sx, scale, bias, out, M, N, K);
    } else {
        scale_quant_kernel<<<N, 256, 0, stream>>>(w, scale, nullptr, K);
        dim3 g((N + 15) / 16, (M + 15) / 16);
        fb_gemm_kernel<<<g, 256, 0, stream>>>(x, w, scale, bias, out, M, N, K);
    }
}